// Round 3
// baseline (248.893 us; speedup 1.0000x reference)
//
#include <hip/hip_runtime.h>
#include <stdint.h>

#define D 128
#define K_NEI 10
#define TILE_M 64   // fused-fallback tile

typedef __bf16 bf16x8 __attribute__((ext_vector_type(8)));
typedef float f32x4 __attribute__((ext_vector_type(4)));

__device__ __forceinline__ uint32_t f2bf(float f) {
    union { float f; uint32_t u; } v; v.f = f;
    uint32_t u = v.u;
    return (u + 0x7FFFu + ((u >> 16) & 1u)) >> 16;   // RNE
}
__device__ __forceinline__ float bf2f(uint32_t h) {
    union { uint32_t u; float f; } v; v.u = h << 16; return v.f;
}
__device__ __forceinline__ uint32_t pack2(float a, float b) {
    return f2bf(a) | (f2bf(b) << 16);
}
__device__ __forceinline__ bf16x8 u4_as_bf16x8(uint4 u) {
    union { uint4 u; bf16x8 b; } v; v.u = u; return v.b;
}
// HW bf16 conversion (compiler emits v_cvt_pk_bf16_f32 for pairs)
__device__ __forceinline__ uint2 cvt4(f32x4 v) {
    union { __bf16 b[4]; uint2 u; } o;
    o.b[0] = (__bf16)v[0]; o.b[1] = (__bf16)v[1];
    o.b[2] = (__bf16)v[2]; o.b[3] = (__bf16)v[3];
    return o.u;
}
__device__ __forceinline__ bf16x8 cvt8(f32x4 lo, f32x4 hi) {
    union { __bf16 b[8]; bf16x8 v; } o;
    o.b[0] = (__bf16)lo[0]; o.b[1] = (__bf16)lo[1];
    o.b[2] = (__bf16)lo[2]; o.b[3] = (__bf16)lo[3];
    o.b[4] = (__bf16)hi[0]; o.b[5] = (__bf16)hi[1];
    o.b[6] = (__bf16)hi[2]; o.b[7] = (__bf16)hi[3];
    return o.v;
}

// ============================================================================
// convert_Wc: W1,W2 [128][256] fp32 -> bf16, SAME layout, with the 0.1
// neighbor-mean scale FOLDED into the k>=128 columns ((0.1x)W^T == x(0.1W)^T).
// Thread t covers flat elements t*8..t*8+7; its column block is (t&31)*8,
// so the agg half (col>=128) is exactly (t & 16) != 0.
// ============================================================================
__global__ void convert_Wc(const float* __restrict__ W1, const float* __restrict__ W2,
                           uint16_t* __restrict__ O1, uint16_t* __restrict__ O2)
{
    const float* W = (blockIdx.x < 16) ? W1 : W2;
    uint16_t*    O = (blockIdx.x < 16) ? O1 : O2;
    int t = (blockIdx.x & 15) * 256 + threadIdx.x;   // 0..4095, 8 elems each
    const float s = (t & 16) ? 0.1f : 1.0f;
    const float* src = W + (size_t)t * 8;
    f32x4 a = *(const f32x4*)src * s;
    f32x4 b = *(const f32x4*)(src + 4) * s;
    uint2 lo = cvt4(a), hi = cvt4(b);
    uint4 o; o.x = lo.x; o.y = lo.y; o.z = hi.x; o.w = hi.y;
    *(uint4*)(O + (size_t)t * 8) = o;
}

// ============================================================================
// sage_fused: out[g] = relu([src[self[g]] | sum_k src[neigh[g][k]]] @ Wc^T)
// (0.1 mean scale pre-folded into Wc's k>=128 columns.)
//
// Zero LDS, zero barriers: each lane gathers EXACTLY the MFMA B-fragment it
// must hold. Lane (r16 = lane&15, q = lane>>4) owns node g = base + r16 and
// k-slices ks*32 + q*8 .. +7:
//   ks 0..3  -> self cols   (4 q-lanes together consume each 128B line fully)
//   ks 4..7  -> fp32 sum over 10 neighbors of the same cols
// MFMA (swapped operands, proven in R2's gemm_k256): mfma(Wfrag, a) with
//   Wfrag: lane holds W[out-col nt*16 + r16][k = ks*32 + q*8 ..] (L2-hot 64KB,
//          re-read per wave -- a one-shot kernel has no W reuse to exploit)
//   D: col = lane&15 = r16 = own node, row = q*4 + reg -> 4 consecutive
//      out-cols per lane -> 8B bf16 / 16B f32 stores.
// The gather's memory latency hides all VALU + MFMA (~95% idle pipes in R2).
// ============================================================================
template <bool SRC_F32, bool OUT_F32>
__global__ __launch_bounds__(256)
void sage_fused(const void* __restrict__ src_,
                const uint16_t* __restrict__ Wc,   // [128][256] bf16, agg half pre-scaled
                const int* __restrict__ self_idx,
                const int* __restrict__ neigh_idx,
                void* __restrict__ out_, int M)
{
    const int tid  = threadIdx.x;
    const int lane = tid & 63;
    const int r16  = lane & 15;
    const int q    = lane >> 4;
    const int g    = blockIdx.x * 64 + (tid >> 6) * 16 + r16;   // node (M % 64 == 0)

    // 10 neighbor indices via 5 x int2 (rows are 40B, 8B aligned)
    const int2* nrow2 = (const int2*)(neigh_idx + (size_t)g * K_NEI);
    int idx[K_NEI];
    #pragma unroll
    for (int k = 0; k < 5; ++k) {
        int2 p = nrow2[k];
        idx[2 * k] = p.x; idx[2 * k + 1] = p.y;
    }
    const int self = self_idx[g];

    bf16x8 a[8];
    f32x4 agg[8];
    #pragma unroll
    for (int x = 0; x < 8; ++x) agg[x] = (f32x4){0.f, 0.f, 0.f, 0.f};

    if (SRC_F32) {
        const float* src  = (const float*)src_;
        const float* srow = src + (size_t)self * D + q * 8;
        #pragma unroll
        for (int ks = 0; ks < 4; ++ks)
            a[ks] = cvt8(*(const f32x4*)(srow + ks * 32),
                         *(const f32x4*)(srow + ks * 32 + 4));
        #pragma unroll
        for (int k = 0; k < K_NEI; ++k) {
            const float* r = src + (size_t)idx[k] * D + q * 8;
            #pragma unroll
            for (int ks = 0; ks < 4; ++ks) {
                agg[2 * ks]     += *(const f32x4*)(r + ks * 32);
                agg[2 * ks + 1] += *(const f32x4*)(r + ks * 32 + 4);
            }
        }
    } else {
        const uint16_t* src = (const uint16_t*)src_;
        #pragma unroll
        for (int ks = 0; ks < 4; ++ks)
            a[ks] = u4_as_bf16x8(*(const uint4*)(src + (size_t)self * D + q * 8 + ks * 32));
        #pragma unroll
        for (int k = 0; k < K_NEI; ++k) {
            const uint16_t* r = src + (size_t)idx[k] * D + q * 8;
            #pragma unroll
            for (int ks = 0; ks < 4; ++ks) {
                uint4 v = *(const uint4*)(r + ks * 32);
                agg[2 * ks]     += (f32x4){bf2f(v.x & 0xFFFFu), bf2f(v.x >> 16),
                                           bf2f(v.y & 0xFFFFu), bf2f(v.y >> 16)};
                agg[2 * ks + 1] += (f32x4){bf2f(v.z & 0xFFFFu), bf2f(v.z >> 16),
                                           bf2f(v.w & 0xFFFFu), bf2f(v.w >> 16)};
            }
        }
    }
    #pragma unroll
    for (int ks = 0; ks < 4; ++ks)
        a[4 + ks] = cvt8(agg[2 * ks], agg[2 * ks + 1]);   // 0.1 folded into Wc

    f32x4 acc[8];
    #pragma unroll
    for (int nt = 0; nt < 8; ++nt) acc[nt] = (f32x4){0.f, 0.f, 0.f, 0.f};

    const uint16_t* wb = Wc + (size_t)r16 * 256 + q * 8;
    #pragma unroll
    for (int nt = 0; nt < 8; ++nt)
        #pragma unroll
        for (int ks = 0; ks < 8; ++ks) {
            bf16x8 w = *(const bf16x8*)(wb + (size_t)nt * 16 * 256 + ks * 32);
            acc[nt] = __builtin_amdgcn_mfma_f32_16x16x32_bf16(w, a[ks], acc[nt], 0, 0, 0);
        }

    // lane stores node g, out-cols nt*16 + q*4 .. +3
    #pragma unroll
    for (int nt = 0; nt < 8; ++nt) {
        f32x4 v = acc[nt];
        v[0] = v[0] > 0.f ? v[0] : 0.f;
        v[1] = v[1] > 0.f ? v[1] : 0.f;
        v[2] = v[2] > 0.f ? v[2] : 0.f;
        v[3] = v[3] > 0.f ? v[3] : 0.f;
        const int col = nt * 16 + q * 4;
        if (OUT_F32)
            *(f32x4*)((float*)out_ + (size_t)g * D + col) = v;
        else
            *(uint2*)((uint16_t*)out_ + (size_t)g * D + col) = cvt4(v);
    }
}

// ============================================================================
// Fallback: R3 fused kernel (proven) — only if ws too small / M not % 64.
// ============================================================================
template <bool FEATS_F32, bool OUT_F32>
__global__ void sage_layer(const void* __restrict__ feats_,
                           const float* __restrict__ W,
                           const int* __restrict__ self_idx,
                           const int* __restrict__ neigh_idx,
                           void* __restrict__ out_)
{
    __shared__ __align__(16) uint16_t Alds[TILE_M * 128];
    __shared__ __align__(16) uint16_t Wlds[128 * 128];

    const int tid  = threadIdx.x;
    const int wave = tid >> 6;
    const int lane = tid & 63;
    const int r16  = lane & 15;
    const int q    = lane >> 4;
    const int G    = blockIdx.x * TILE_M;

    const float*    feats_f = (const float*)feats_;
    const uint16_t* feats_b = (const uint16_t*)feats_;

    f32x4 acc[8];
    #pragma unroll
    for (int nt = 0; nt < 8; ++nt) acc[nt] = (f32x4){0.f, 0.f, 0.f, 0.f};

    for (int half = 0; half < 2; ++half) {
        #pragma unroll
        for (int it = 0; it < 8; ++it) {
            int t = it * 256 + tid;
            int j = t >> 4, c = t & 15;
            const float* src = W + (size_t)j * 256 + half * 128 + c * 8;
            f32x4 w0 = *(const f32x4*)(src);
            f32x4 w1 = *(const f32x4*)(src + 4);
            uint4 o;
            o.x = pack2(w0[0], w0[1]); o.y = pack2(w0[2], w0[3]);
            o.z = pack2(w1[0], w1[1]); o.w = pack2(w1[2], w1[3]);
            int cs = c ^ (j & 15);
            *(uint4*)(Wlds + j * 128 + cs * 8) = o;
        }
        if (half == 0) {
            #pragma unroll
            for (int it = 0; it < 4; ++it) {
                int t = it * 256 + tid;
                int n = t >> 4, c = t & 15;
                int node = self_idx[G + n];
                uint4 o;
                if (FEATS_F32) {
                    const float* src = feats_f + (size_t)node * D + c * 8;
                    f32x4 f0 = *(const f32x4*)(src);
                    f32x4 f1 = *(const f32x4*)(src + 4);
                    o.x = pack2(f0[0], f0[1]); o.y = pack2(f0[2], f0[3]);
                    o.z = pack2(f1[0], f1[1]); o.w = pack2(f1[2], f1[3]);
                } else {
                    o = *(const uint4*)(feats_b + (size_t)node * D + c * 8);
                }
                int cs = c ^ (n & 15);
                *(uint4*)(Alds + n * 128 + cs * 8) = o;
            }
        } else {
            #pragma unroll
            for (int it = 0; it < 4; ++it) {
                int t = it * 256 + tid;
                int n = t >> 4, c = t & 15;
                const int* nrow = neigh_idx + (size_t)(G + n) * K_NEI;
                float s0=0,s1=0,s2=0,s3=0,s4=0,s5=0,s6=0,s7=0;
                #pragma unroll
                for (int k = 0; k < K_NEI; ++k) {
                    if (FEATS_F32) {
                        const float* src = feats_f + (size_t)nrow[k] * D + c * 8;
                        f32x4 f0 = *(const f32x4*)(src);
                        f32x4 f1 = *(const f32x4*)(src + 4);
                        s0 += f0[0]; s1 += f0[1]; s2 += f0[2]; s3 += f0[3];
                        s4 += f1[0]; s5 += f1[1]; s6 += f1[2]; s7 += f1[3];
                    } else {
                        uint4 v = *(const uint4*)(feats_b + (size_t)nrow[k] * D + c * 8);
                        s0 += bf2f(v.x & 0xFFFFu); s1 += bf2f(v.x >> 16);
                        s2 += bf2f(v.y & 0xFFFFu); s3 += bf2f(v.y >> 16);
                        s4 += bf2f(v.z & 0xFFFFu); s5 += bf2f(v.z >> 16);
                        s6 += bf2f(v.w & 0xFFFFu); s7 += bf2f(v.w >> 16);
                    }
                }
                const float inv = 0.1f;
                uint4 o;
                o.x = pack2(s0 * inv, s1 * inv);
                o.y = pack2(s2 * inv, s3 * inv);
                o.z = pack2(s4 * inv, s5 * inv);
                o.w = pack2(s6 * inv, s7 * inv);
                int cs = c ^ (n & 15);
                *(uint4*)(Alds + n * 128 + cs * 8) = o;
            }
        }
        __syncthreads();

        #pragma unroll
        for (int ks = 0; ks < 4; ++ks) {
            int cidx = ks * 4 + q;
            bf16x8 a = *(const bf16x8*)(Alds + (wave * 16 + r16) * 128 + ((cidx ^ r16) * 8));
            bf16x8 b[8];
            #pragma unroll
            for (int nt = 0; nt < 8; ++nt) {
                int jj = nt * 16 + r16;
                b[nt] = *(const bf16x8*)(Wlds + jj * 128 + ((cidx ^ r16) * 8));
            }
            #pragma unroll
            for (int nt = 0; nt < 8; ++nt)
                acc[nt] = __builtin_amdgcn_mfma_f32_16x16x32_bf16(a, b[nt], acc[nt], 0, 0, 0);
        }
        __syncthreads();
    }

    const int row_base = G + wave * 16 + q * 4;
    #pragma unroll
    for (int nt = 0; nt < 8; ++nt) {
        int col = nt * 16 + r16;
        #pragma unroll
        for (int r = 0; r < 4; ++r) {
            float v = acc[nt][r];
            v = v > 0.f ? v : 0.f;
            if (OUT_F32) ((float*)out_)[(size_t)(row_base + r) * D + col] = v;
            else ((uint16_t*)out_)[(size_t)(row_base + r) * D + col] = (uint16_t)f2bf(v);
        }
    }
}

extern "C" void kernel_launch(void* const* d_in, const int* in_sizes, int n_in,
                              void* d_out, int out_size, void* d_ws, size_t ws_size,
                              hipStream_t stream) {
    const float* raw = (const float*)d_in[0];          // [200000][128] fp32
    const float* W1  = (const float*)d_in[1];          // [128][256] fp32
    const float* W2  = (const float*)d_in[2];          // [128][256] fp32
    const int* layer1_nodes = (const int*)d_in[3];     // [81920]
    const int* neigh0       = (const int*)d_in[4];     // [81920][10]
    const int* map_batch    = (const int*)d_in[5];     // [8192]
    const int* neigh1       = (const int*)d_in[6];     // [8192][10]

    const int N1 = in_sizes[3];            // 81920
    const int B  = in_sizes[5];            // 8192

    const size_t szH1 = (size_t)N1 * 128 * 2;          // 21.0 MB
    const size_t szW  = 128 * 256 * 2;                 // 64 KB
    const size_t need = szH1 + 2 * szW;

    if (ws_size >= need && (N1 % 64) == 0 && (B % 64) == 0) {
        uint16_t* h1  = (uint16_t*)d_ws;
        uint16_t* W1c = h1 + (size_t)N1 * 128;
        uint16_t* W2c = W1c + 128 * 256;

        convert_Wc<<<32, 256, 0, stream>>>(W1, W2, W1c, W2c);

        // Layer 1: gather + mean + GEMM in ONE kernel (MFMA hidden under
        // the gather's memory latency; no intermediate C tensor).
        sage_fused<true,  false><<<N1 / 64, 256, 0, stream>>>(raw, W1c, layer1_nodes, neigh0, h1, N1);

        // Layer 2: same, batch rows, fp32 output.
        sage_fused<false, true ><<<B  / 64, 256, 0, stream>>>(h1,  W2c, map_batch,    neigh1, d_out, B);
        return;
    }

    // Fallback: R3 fused path
    uint16_t* h1 = (uint16_t*)d_ws;
    sage_layer<true,  false><<<N1 / TILE_M, 256, 0, stream>>>(raw, W1, layer1_nodes, neigh0, h1);
    sage_layer<false, true ><<<B  / TILE_M, 256, 0, stream>>>(h1,  W2, map_batch,    neigh1, d_out);
}